// Round 1
// baseline (200.674 us; speedup 1.0000x reference)
//
#include <hip/hip_runtime.h>
#include <hip/hip_bf16.h>

typedef unsigned short u16;
typedef unsigned int u32;

#define BATCH 4
#define NLEN 2048
#define DIM 512
#define LDSK 40   // 32 + 8 pad (keeps 16B alignment of frag reads)

typedef __attribute__((ext_vector_type(8))) __bf16 bf16x8;
typedef __attribute__((ext_vector_type(4))) float f32x4;

__device__ __forceinline__ u16 f32_to_bf16(float f) {
  union { float f; u32 u; } v; v.f = f;
  u32 u = v.u;
  return (u16)((u + 0x7FFFu + ((u >> 16) & 1u)) >> 16);
}

// stage 16 f32 -> bf16 into LDS
__device__ __forceinline__ void stage16_f32(u16* dst, const float* src) {
#pragma unroll
  for (int i = 0; i < 4; ++i) {
    float4 v = *(const float4*)(src + i * 4);
    dst[i * 4 + 0] = f32_to_bf16(v.x);
    dst[i * 4 + 1] = f32_to_bf16(v.y);
    dst[i * 4 + 2] = f32_to_bf16(v.z);
    dst[i * 4 + 3] = f32_to_bf16(v.w);
  }
}

// stage 16 bf16 (raw u16) into LDS
__device__ __forceinline__ void stage16_bf16(u16* dst, const u16* src) {
  *(uint4*)dst = *(const uint4*)src;
  *(uint4*)(dst + 8) = *(const uint4*)(src + 8);
}

// one BK=32 step: 4x4 frags of 16x16x32 per wave (wave computes 64x64)
__device__ __forceinline__ void mma_step(const u16 As[][LDSK], const u16 Bs[][LDSK],
                                         f32x4 acc[4][4], int wm, int wn, int lr, int lk) {
  bf16x8 af[4], bfr[4];
#pragma unroll
  for (int m = 0; m < 4; ++m)
    af[m] = *(const bf16x8*)&As[wm + m * 16 + lr][lk];
#pragma unroll
  for (int n = 0; n < 4; ++n)
    bfr[n] = *(const bf16x8*)&Bs[wn + n * 16 + lr][lk];
#pragma unroll
  for (int m = 0; m < 4; ++m)
#pragma unroll
    for (int n = 0; n < 4; ++n)
      acc[m][n] = __builtin_amdgcn_mfma_f32_16x16x32_bf16(af[m], bfr[n], acc[m][n], 0, 0, 0);
}

// ---------------- K1: q projection  C[8192][512] = A(query) . W_in^T ----------------
__global__ __launch_bounds__(256) void k_qproj(const float* __restrict__ query,
                                               const float* __restrict__ W_in,
                                               u16* __restrict__ qp, u16* __restrict__ qt) {
  __shared__ u16 As[128][LDSK];
  __shared__ u16 Bs[128][LDSK];
  const int t = threadIdx.x;
  const int trow = t >> 1, thalf = (t & 1) * 16;
  const int lane = t & 63, wid = t >> 6;
  const int wm = (wid >> 1) * 64, wn = (wid & 1) * 64;
  const int lr = lane & 15, lk = (lane >> 4) * 8;
  const int rbase = blockIdx.y * 128;  // over b*n = 8192
  const int cbase = blockIdx.x * 128;  // over e = 512
  const int rg = rbase + trow;
  const int bb = rg >> 11, nn = rg & 2047;
  const float* aRow = query + (size_t)(nn * BATCH + bb) * DIM;
  const float* bRow = W_in + (size_t)(cbase + trow) * DIM;
  f32x4 acc[4][4] = {};
  for (int k0 = 0; k0 < DIM; k0 += 32) {
    stage16_f32(&As[trow][thalf], aRow + k0 + thalf);
    stage16_f32(&Bs[trow][thalf], bRow + k0 + thalf);
    __syncthreads();
    mma_step(As, Bs, acc, wm, wn, lr, lk);
    __syncthreads();
  }
#pragma unroll
  for (int m = 0; m < 4; ++m)
#pragma unroll
    for (int n = 0; n < 4; ++n)
#pragma unroll
      for (int j = 0; j < 4; ++j) {
        int row = rbase + wm + m * 16 + (lane >> 4) * 4 + j;
        int col = cbase + wn + n * 16 + lr;
        u16 v = f32_to_bf16(acc[m][n][j]);
        qp[(size_t)row * DIM + col] = v;
        int b2 = row >> 11, n2 = row & 2047;
        qt[(size_t)(b2 * DIM + col) * NLEN + n2] = v;
      }
}

// ---------------- K2: scores  S[b] = Q[b] . Q[b]^T  (lower-tri blocks only) ----------------
__global__ __launch_bounds__(256) void k_scores(const u16* __restrict__ qp,
                                                float* __restrict__ w) {
  const int mt = blockIdx.x, nt = blockIdx.y, b = blockIdx.z;
  if (mt > nt) return;  // fully-masked block
  __shared__ u16 As[128][LDSK];
  __shared__ u16 Bs[128][LDSK];
  const int t = threadIdx.x;
  const int trow = t >> 1, thalf = (t & 1) * 16;
  const int lane = t & 63, wid = t >> 6;
  const int wm = (wid >> 1) * 64, wn = (wid & 1) * 64;
  const int lr = lane & 15, lk = (lane >> 4) * 8;
  const u16* aRow = qp + (size_t)(b * NLEN + nt * 128 + trow) * DIM;
  const u16* bRow = qp + (size_t)(b * NLEN + mt * 128 + trow) * DIM;
  f32x4 acc[4][4] = {};
  for (int k0 = 0; k0 < DIM; k0 += 32) {
    stage16_bf16(&As[trow][thalf], aRow + k0 + thalf);
    stage16_bf16(&Bs[trow][thalf], bRow + k0 + thalf);
    __syncthreads();
    mma_step(As, Bs, acc, wm, wn, lr, lk);
    __syncthreads();
  }
  float* wb = w + (size_t)b * NLEN * NLEN;
#pragma unroll
  for (int m = 0; m < 4; ++m)
#pragma unroll
    for (int n = 0; n < 4; ++n)
#pragma unroll
      for (int j = 0; j < 4; ++j) {
        int row = nt * 128 + wm + m * 16 + (lane >> 4) * 4 + j;
        int col = mt * 128 + wn + n * 16 + lr;
        wb[(size_t)row * NLEN + col] = acc[m][n][j];
      }
}

// ---------------- K3: causal softmax in-place in weights region ----------------
__global__ __launch_bounds__(256) void k_softmax(float* __restrict__ w) {
  const int n = blockIdx.x, b = blockIdx.y;
  float* wrow = w + ((size_t)b * NLEN + n) * NLEN;
  const int t = threadIdx.x;
  __shared__ float srow[NLEN];
  __shared__ float red[4];
  if (n == 0) {
    for (int m = t; m < NLEN; m += 256) wrow[m] = 0.0f;
    return;
  }
  const int lane = t & 63, wid = t >> 6;
  float mx = -1e38f;
  for (int m = t; m < n; m += 256) {
    float s = wrow[m];
    srow[m] = s;
    mx = fmaxf(mx, s);
  }
#pragma unroll
  for (int off = 32; off > 0; off >>= 1) mx = fmaxf(mx, __shfl_xor(mx, off));
  if (lane == 0) red[wid] = mx;
  __syncthreads();
  mx = fmaxf(fmaxf(red[0], red[1]), fmaxf(red[2], red[3]));
  float sum = 0.f;
  for (int m = t; m < n; m += 256) {
    float e = __expf(srow[m] - mx);
    srow[m] = e;
    sum += e;
  }
#pragma unroll
  for (int off = 32; off > 0; off >>= 1) sum += __shfl_xor(sum, off);
  __syncthreads();  // everyone done reading red (max)
  if (lane == 0) red[wid] = sum;
  __syncthreads();
  float inv = 1.0f / (red[0] + red[1] + red[2] + red[3]);
  for (int m = t; m < NLEN; m += 256) wrow[m] = (m < n) ? srow[m] * inv : 0.0f;
}

// ---------------- K4: mix[b] = W[b] . Q[b]   (K truncated at diagonal) ----------------
__global__ __launch_bounds__(256) void k_mix(const float* __restrict__ w,
                                             const u16* __restrict__ qt,
                                             u16* __restrict__ mixo) {
  const int dt = blockIdx.x, nt = blockIdx.y, b = blockIdx.z;
  __shared__ u16 As[128][LDSK];
  __shared__ u16 Bs[128][LDSK];
  const int t = threadIdx.x;
  const int trow = t >> 1, thalf = (t & 1) * 16;
  const int lane = t & 63, wid = t >> 6;
  const int wm = (wid >> 1) * 64, wn = (wid & 1) * 64;
  const int lr = lane & 15, lk = (lane >> 4) * 8;
  const float* aRow = w + (size_t)(b * NLEN + nt * 128 + trow) * NLEN;
  const u16* bRow = qt + (size_t)(b * DIM + dt * 128 + trow) * NLEN;
  const int Kmax = (nt + 1) * 128;  // weights are zero for m >= n
  f32x4 acc[4][4] = {};
  for (int k0 = 0; k0 < Kmax; k0 += 32) {
    stage16_f32(&As[trow][thalf], aRow + k0 + thalf);
    stage16_bf16(&Bs[trow][thalf], bRow + k0 + thalf);
    __syncthreads();
    mma_step(As, Bs, acc, wm, wn, lr, lk);
    __syncthreads();
  }
#pragma unroll
  for (int m = 0; m < 4; ++m)
#pragma unroll
    for (int n = 0; n < 4; ++n)
#pragma unroll
      for (int j = 0; j < 4; ++j) {
        int row = nt * 128 + wm + m * 16 + (lane >> 4) * 4 + j;
        int col = dt * 128 + wn + n * 16 + lr;
        mixo[(size_t)(b * NLEN + row) * DIM + col] = f32_to_bf16(acc[m][n][j]);
      }
}

// ---------------- K5: out = selu(concat(mix, q) . W_out^T), transposed write ----------------
__global__ __launch_bounds__(256) void k_out(const u16* __restrict__ mixo,
                                             const u16* __restrict__ qp,
                                             const float* __restrict__ W_out,
                                             float* __restrict__ out) {
  __shared__ u16 As[128][LDSK];
  __shared__ u16 Bs[128][LDSK];
  const int et = blockIdx.x, rt = blockIdx.y;
  const int t = threadIdx.x;
  const int trow = t >> 1, thalf = (t & 1) * 16;
  const int lane = t & 63, wid = t >> 6;
  const int wm = (wid >> 1) * 64, wn = (wid & 1) * 64;
  const int lr = lane & 15, lk = (lane >> 4) * 8;
  const int rg = rt * 128 + trow;
  const u16* mRow = mixo + (size_t)rg * DIM;
  const u16* qRow = qp + (size_t)rg * DIM;
  const float* bRow = W_out + (size_t)(et * 128 + trow) * (2 * DIM);
  f32x4 acc[4][4] = {};
  for (int k0 = 0; k0 < 2 * DIM; k0 += 32) {
    const u16* src = (k0 < DIM) ? (mRow + k0) : (qRow + (k0 - DIM));
    stage16_bf16(&As[trow][thalf], src + thalf);
    stage16_f32(&Bs[trow][thalf], bRow + k0 + thalf);
    __syncthreads();
    mma_step(As, Bs, acc, wm, wn, lr, lk);
    __syncthreads();
  }
  const float sc = 1.0507009873554805f;
  const float al = 1.6732632423543772f;
#pragma unroll
  for (int m = 0; m < 4; ++m)
#pragma unroll
    for (int n = 0; n < 4; ++n)
#pragma unroll
      for (int j = 0; j < 4; ++j) {
        int row = rt * 128 + wm + m * 16 + (lane >> 4) * 4 + j;
        int col = et * 128 + wn + n * 16 + lr;
        int b2 = row >> 11, n2 = row & 2047;
        float v = acc[m][n][j];
        v = (v > 0.f) ? sc * v : sc * al * (__expf(v) - 1.f);
        out[(size_t)(n2 * BATCH + b2) * DIM + col] = v;
      }
}

extern "C" void kernel_launch(void* const* d_in, const int* in_sizes, int n_in,
                              void* d_out, int out_size, void* d_ws, size_t ws_size,
                              hipStream_t stream) {
  const float* query = (const float*)d_in[0];
  const float* W_in = (const float*)d_in[1];
  const float* W_out = (const float*)d_in[2];
  float* out0 = (float*)d_out;                     // [NLEN][BATCH][DIM]
  float* w = out0 + (size_t)NLEN * BATCH * DIM;    // weights region [BATCH][NLEN][NLEN]
  u16* qp = (u16*)d_ws;                            // [BATCH][NLEN][DIM] bf16
  u16* qt = qp + (size_t)BATCH * NLEN * DIM;       // [BATCH][DIM][NLEN] bf16
  u16* mixo = qt + (size_t)BATCH * NLEN * DIM;     // [BATCH][NLEN][DIM] bf16

  dim3 blk(256);
  k_qproj<<<dim3(DIM / 128, (BATCH * NLEN) / 128), blk, 0, stream>>>(query, W_in, qp, qt);
  k_scores<<<dim3(NLEN / 128, NLEN / 128, BATCH), blk, 0, stream>>>(qp, w);
  k_softmax<<<dim3(NLEN, BATCH), blk, 0, stream>>>(w);
  k_mix<<<dim3(DIM / 128, NLEN / 128, BATCH), blk, 0, stream>>>(w, qt, mixo);
  k_out<<<dim3(DIM / 128, (BATCH * NLEN) / 128), blk, 0, stream>>>(mixo, qp, W_out, out0);
}

// Round 2
// 159.338 us; speedup vs baseline: 1.2594x; 1.2594x over previous
//
#include <hip/hip_runtime.h>
#include <hip/hip_bf16.h>

typedef unsigned short u16;
typedef unsigned int u32;

#define BATCH 4
#define NLEN 2048
#define DIM 512
#define LDSK 40   // 32 + 8 pad

typedef __attribute__((ext_vector_type(8))) __bf16 bf16x8;
typedef __attribute__((ext_vector_type(4))) float f32x4;

__device__ __forceinline__ u16 f32_to_bf16(float f) {
  union { float f; u32 u; } v; v.f = f;
  u32 u = v.u;
  return (u16)((u + 0x7FFFu + ((u >> 16) & 1u)) >> 16);
}

__device__ __forceinline__ void stage16_f32(u16* dst, const float* src) {
#pragma unroll
  for (int i = 0; i < 4; ++i) {
    float4 v = *(const float4*)(src + i * 4);
    dst[i * 4 + 0] = f32_to_bf16(v.x);
    dst[i * 4 + 1] = f32_to_bf16(v.y);
    dst[i * 4 + 2] = f32_to_bf16(v.z);
    dst[i * 4 + 3] = f32_to_bf16(v.w);
  }
}

__device__ __forceinline__ void stage16_bf16(u16* dst, const u16* src) {
  *(uint4*)dst = *(const uint4*)src;
  *(uint4*)(dst + 8) = *(const uint4*)(src + 8);
}

__device__ __forceinline__ u32 addpk_bf16(u32 a, u32 b) {
  float a0 = __uint_as_float(a << 16), a1 = __uint_as_float(a & 0xffff0000u);
  float b0 = __uint_as_float(b << 16), b1 = __uint_as_float(b & 0xffff0000u);
  float r0 = a0 + b0, r1 = a1 + b1;
  return (u32)f32_to_bf16(r0) | ((u32)f32_to_bf16(r1) << 16);
}

// sum two bf16 streams of 16 elems into LDS
__device__ __forceinline__ void stage16_add(u16* dst, const u16* s0, const u16* s1) {
  uint4 a0 = *(const uint4*)s0, b0 = *(const uint4*)s1;
  uint4 a1 = *(const uint4*)(s0 + 8), b1 = *(const uint4*)(s1 + 8);
  uint4 o0, o1;
  o0.x = addpk_bf16(a0.x, b0.x); o0.y = addpk_bf16(a0.y, b0.y);
  o0.z = addpk_bf16(a0.z, b0.z); o0.w = addpk_bf16(a0.w, b0.w);
  o1.x = addpk_bf16(a1.x, b1.x); o1.y = addpk_bf16(a1.y, b1.y);
  o1.z = addpk_bf16(a1.z, b1.z); o1.w = addpk_bf16(a1.w, b1.w);
  *(uint4*)dst = o0;
  *(uint4*)(dst + 8) = o1;
}

__device__ __forceinline__ void mma_step(const u16 As[][LDSK], const u16 Bs[][LDSK],
                                         f32x4 acc[4][4], int wm, int wn, int lr, int lk) {
  bf16x8 af[4], bfr[4];
#pragma unroll
  for (int m = 0; m < 4; ++m)
    af[m] = *(const bf16x8*)&As[wm + m * 16 + lr][lk];
#pragma unroll
  for (int n = 0; n < 4; ++n)
    bfr[n] = *(const bf16x8*)&Bs[wn + n * 16 + lr][lk];
#pragma unroll
  for (int m = 0; m < 4; ++m)
#pragma unroll
    for (int n = 0; n < 4; ++n)
      acc[m][n] = __builtin_amdgcn_mfma_f32_16x16x32_bf16(af[m], bfr[n], acc[m][n], 0, 0, 0);
}

// ---------------- K1: q projection + transposed copy ----------------
__global__ __launch_bounds__(256) void k_qproj(const float* __restrict__ query,
                                               const float* __restrict__ W_in,
                                               u16* __restrict__ qp, u16* __restrict__ qt) {
  __shared__ u16 As[128][LDSK];
  __shared__ u16 Bs[128][LDSK];
  __shared__ u16 tbuf[128][136];  // [d_local][n_local], 16B-aligned rows
  const int t = threadIdx.x;
  const int trow = t >> 1, thalf = (t & 1) * 16;
  const int lane = t & 63, wid = t >> 6;
  const int wm = (wid >> 1) * 64, wn = (wid & 1) * 64;
  const int lr = lane & 15, lk = (lane >> 4) * 8;
  const int rbase = blockIdx.y * 128;  // over b*n = 8192
  const int cbase = blockIdx.x * 128;  // over e = 512
  const int rg = rbase + trow;
  const int bb = rg >> 11, nn = rg & 2047;
  const float* aRow = query + (size_t)(nn * BATCH + bb) * DIM;
  const float* bRow = W_in + (size_t)(cbase + trow) * DIM;
  f32x4 acc[4][4] = {};
  for (int k0 = 0; k0 < DIM; k0 += 32) {
    stage16_f32(&As[trow][thalf], aRow + k0 + thalf);
    stage16_f32(&Bs[trow][thalf], bRow + k0 + thalf);
    __syncthreads();
    mma_step(As, Bs, acc, wm, wn, lr, lk);
    __syncthreads();
  }
#pragma unroll
  for (int m = 0; m < 4; ++m)
#pragma unroll
    for (int n = 0; n < 4; ++n)
#pragma unroll
      for (int j = 0; j < 4; ++j) {
        int rl = wm + m * 16 + (lane >> 4) * 4 + j;
        int cl = wn + n * 16 + lr;
        u16 v = f32_to_bf16(acc[m][n][j]);
        qp[(size_t)(rbase + rl) * DIM + cbase + cl] = v;
        tbuf[cl][rl] = v;
      }
  __syncthreads();
  const int bb0 = rbase >> 11, nbase = rbase & 2047;
#pragma unroll
  for (int i = 0; i < 8; ++i) {
    int idx = t + i * 256;
    int dl = idx >> 4, c = idx & 15;
    uint4 v = *(const uint4*)&tbuf[dl][c * 8];
    *(uint4*)(qt + (size_t)(bb0 * DIM + cbase + dl) * NLEN + nbase + c * 8) = v;
  }
}

// ---------------- K2: scores -> packed lower-tri bf16 tiles ----------------
__global__ __launch_bounds__(256) void k_scores(const u16* __restrict__ qp,
                                                u16* __restrict__ swf) {
  const int mt = blockIdx.x, nt = blockIdx.y, b = blockIdx.z;
  if (mt > nt) return;
  __shared__ u16 As[128][LDSK];
  __shared__ u16 Bs[128][LDSK];
  const int t = threadIdx.x;
  const int trow = t >> 1, thalf = (t & 1) * 16;
  const int lane = t & 63, wid = t >> 6;
  const int wm = (wid >> 1) * 64, wn = (wid & 1) * 64;
  const int lr = lane & 15, lk = (lane >> 4) * 8;
  const u16* aRow = qp + (size_t)(b * NLEN + nt * 128 + trow) * DIM;
  const u16* bRow = qp + (size_t)(b * NLEN + mt * 128 + trow) * DIM;
  f32x4 acc[4][4] = {};
  for (int k0 = 0; k0 < DIM; k0 += 32) {
    stage16_bf16(&As[trow][thalf], aRow + k0 + thalf);
    stage16_bf16(&Bs[trow][thalf], bRow + k0 + thalf);
    __syncthreads();
    mma_step(As, Bs, acc, wm, wn, lr, lk);
    __syncthreads();
  }
  u16* wtile = swf + ((size_t)(b * 136 + nt * (nt + 1) / 2 + mt) << 14);
#pragma unroll
  for (int m = 0; m < 4; ++m)
#pragma unroll
    for (int n = 0; n < 4; ++n)
#pragma unroll
      for (int j = 0; j < 4; ++j) {
        int rl = wm + m * 16 + (lane >> 4) * 4 + j;
        int cl = wn + n * 16 + lr;
        wtile[rl * 128 + cl] = f32_to_bf16(acc[m][n][j]);
      }
}

// ---------------- K3: softmax: bf16 packed scores -> f32 weights + bf16 probs ----------------
__global__ __launch_bounds__(256) void k_softmax(u16* __restrict__ swf, float* __restrict__ w) {
  const int n = blockIdx.x, b = blockIdx.y;
  const int t = threadIdx.x;
  float* wrow = w + ((size_t)b * NLEN + n) * NLEN;
  const int nt = n >> 7;
  const size_t tb = ((size_t)(b * 136 + nt * (nt + 1) / 2) << 14) + ((size_t)(n & 127) << 7);
  __shared__ float srow[NLEN];
  __shared__ float red[4];
  if (n == 0) {
    for (int i = t; i < NLEN / 4; i += 256) ((float4*)wrow)[i] = float4{0, 0, 0, 0};
    if (t < 16) ((uint4*)(swf + tb))[t] = uint4{0, 0, 0, 0};
    return;
  }
  const int lane = t & 63, wid = t >> 6;
  const int nchunk = (nt + 1) * 16;  // uint4 chunks of 8 u16 (tile stride 16384 u16)
  float mx = -1e38f;
  for (int idx = t; idx < nchunk; idx += 256) {
    const int mt = idx >> 4, c = idx & 15;
    uint4 rv = *(const uint4*)(swf + tb + ((size_t)mt << 14) + c * 8);
    int m0 = mt * 128 + c * 8;
    u32 wds[4] = {rv.x, rv.y, rv.z, rv.w};
#pragma unroll
    for (int wi = 0; wi < 4; ++wi) {
      float v0 = __uint_as_float(wds[wi] << 16);
      float v1 = __uint_as_float(wds[wi] & 0xffff0000u);
      int m = m0 + wi * 2;
      srow[m] = v0; srow[m + 1] = v1;
      if (m < n) mx = fmaxf(mx, v0);
      if (m + 1 < n) mx = fmaxf(mx, v1);
    }
  }
#pragma unroll
  for (int off = 32; off; off >>= 1) mx = fmaxf(mx, __shfl_xor(mx, off));
  if (lane == 0) red[wid] = mx;
  __syncthreads();
  mx = fmaxf(fmaxf(red[0], red[1]), fmaxf(red[2], red[3]));
  float sum = 0.f;
  for (int m = t; m < n; m += 256) {
    float e = __expf(srow[m] - mx);
    srow[m] = e;
    sum += e;
  }
#pragma unroll
  for (int off = 32; off; off >>= 1) sum += __shfl_xor(sum, off);
  __syncthreads();
  if (lane == 0) red[wid] = sum;
  __syncthreads();
  float inv = 1.0f / (red[0] + red[1] + red[2] + red[3]);
  {
    int m0 = t * 8;
    float vals[8];
#pragma unroll
    for (int e = 0; e < 8; ++e) { int m = m0 + e; vals[e] = (m < n) ? srow[m] * inv : 0.f; }
    ((float4*)wrow)[t * 2] = float4{vals[0], vals[1], vals[2], vals[3]};
    ((float4*)wrow)[t * 2 + 1] = float4{vals[4], vals[5], vals[6], vals[7]};
  }
  for (int idx = t; idx < nchunk; idx += 256) {
    const int mt = idx >> 4, c = idx & 15;
    int m0 = mt * 128 + c * 8;
    u32 wo[4];
#pragma unroll
    for (int wi = 0; wi < 4; ++wi) {
      int m = m0 + wi * 2;
      float v0 = (m < n) ? srow[m] * inv : 0.f;
      float v1 = (m + 1 < n) ? srow[m + 1] * inv : 0.f;
      wo[wi] = (u32)f32_to_bf16(v0) | ((u32)f32_to_bf16(v1) << 16);
    }
    *(uint4*)(swf + tb + ((size_t)mt << 14) + c * 8) = uint4{wo[0], wo[1], wo[2], wo[3]};
  }
}

// ---------------- K4: mix partials, balanced split-K ----------------
__global__ __launch_bounds__(256) void k_mix(const u16* __restrict__ swf,
                                             const u16* __restrict__ qt,
                                             u16* __restrict__ mix0, u16* __restrict__ mix1) {
  // 384 blocks: b in 0..3, dt in 0..3; per (b,dt): nt>=8 split into 2 K-chunks (heavy first)
  const int b = blockIdx.x / 96;
  const int r = blockIdx.x % 96;
  const int dt = r / 24;
  const int jj = r % 24;
  int nt, ks, ke, half;
  if (jj < 16) {
    nt = 15 - (jj >> 1);
    half = jj & 1;
    int s = nt + 1, c0 = (s + 1) >> 1;
    ks = half ? c0 : 0;
    ke = half ? s : c0;
  } else {
    nt = 23 - jj; ks = 0; ke = nt + 1; half = 0;
  }
  __shared__ u16 As[128][LDSK];
  __shared__ u16 Bs[128][LDSK];
  const int t = threadIdx.x;
  const int trow = t >> 1, thalf = (t & 1) * 16;
  const int lane = t & 63, wid = t >> 6;
  const int wm = (wid >> 1) * 64, wn = (wid & 1) * 64;
  const int lr = lane & 15, lk = (lane >> 4) * 8;
  const size_t tribase = (size_t)(b * 136 + nt * (nt + 1) / 2) << 14;
  const u16* bRow = qt + (size_t)(b * DIM + dt * 128 + trow) * NLEN;
  f32x4 acc[4][4] = {};
  for (int kstep = ks * 4; kstep < ke * 4; ++kstep) {
    const int k0 = kstep * 32;
    const int mt = k0 >> 7;
    const u16* aRow = swf + tribase + ((size_t)mt << 14) + trow * 128 + (k0 & 127);
    stage16_bf16(&As[trow][thalf], aRow + thalf);
    stage16_bf16(&Bs[trow][thalf], bRow + k0 + thalf);
    __syncthreads();
    mma_step(As, Bs, acc, wm, wn, lr, lk);
    __syncthreads();
  }
  u16* dst = half ? mix1 : mix0;
#pragma unroll
  for (int m = 0; m < 4; ++m)
#pragma unroll
    for (int n = 0; n < 4; ++n)
#pragma unroll
      for (int j = 0; j < 4; ++j) {
        int row = nt * 128 + wm + m * 16 + (lane >> 4) * 4 + j;
        int col = dt * 128 + wn + n * 16 + lr;
        dst[(size_t)(b * NLEN + row) * DIM + col] = f32_to_bf16(acc[m][n][j]);
      }
}

// ---------------- K5: out = selu(concat(mix0[+mix1], q) . W_out^T) ----------------
__global__ __launch_bounds__(256) void k_out(const u16* __restrict__ mix0,
                                             const u16* __restrict__ mix1,
                                             const u16* __restrict__ qp,
                                             const float* __restrict__ W_out,
                                             float* __restrict__ out) {
  __shared__ u16 As[128][LDSK];
  __shared__ u16 Bs[128][LDSK];
  const int et = blockIdx.x, rt = blockIdx.y;
  const int t = threadIdx.x;
  const int trow = t >> 1, thalf = (t & 1) * 16;
  const int lane = t & 63, wid = t >> 6;
  const int wm = (wid >> 1) * 64, wn = (wid & 1) * 64;
  const int lr = lane & 15, lk = (lane >> 4) * 8;
  const int rg = rt * 128 + trow;
  const int nt = rt & 15;  // n-tile within batch
  const u16* m0Row = mix0 + (size_t)rg * DIM;
  const u16* m1Row = mix1 + (size_t)rg * DIM;
  const u16* qRow = qp + (size_t)rg * DIM;
  const float* bRow = W_out + (size_t)(et * 128 + trow) * (2 * DIM);
  f32x4 acc[4][4] = {};
  for (int k0 = 0; k0 < 2 * DIM; k0 += 32) {
    if (k0 < DIM) {
      if (nt >= 8)
        stage16_add(&As[trow][thalf], m0Row + k0 + thalf, m1Row + k0 + thalf);
      else
        stage16_bf16(&As[trow][thalf], m0Row + k0 + thalf);
    } else {
      stage16_bf16(&As[trow][thalf], qRow + (k0 - DIM) + thalf);
    }
    stage16_f32(&Bs[trow][thalf], bRow + k0 + thalf);
    __syncthreads();
    mma_step(As, Bs, acc, wm, wn, lr, lk);
    __syncthreads();
  }
  const float sc = 1.0507009873554805f;
  const float al = 1.6732632423543772f;
#pragma unroll
  for (int m = 0; m < 4; ++m)
#pragma unroll
    for (int n = 0; n < 4; ++n)
#pragma unroll
      for (int j = 0; j < 4; ++j) {
        int row = rt * 128 + wm + m * 16 + (lane >> 4) * 4 + j;
        int col = et * 128 + wn + n * 16 + lr;
        int b2 = row >> 11, n2 = row & 2047;
        float v = acc[m][n][j];
        v = (v > 0.f) ? sc * v : sc * al * (__expf(v) - 1.f);
        out[(size_t)(n2 * BATCH + b2) * DIM + col] = v;
      }
}

extern "C" void kernel_launch(void* const* d_in, const int* in_sizes, int n_in,
                              void* d_out, int out_size, void* d_ws, size_t ws_size,
                              hipStream_t stream) {
  const float* query = (const float*)d_in[0];
  const float* W_in = (const float*)d_in[1];
  const float* W_out = (const float*)d_in[2];
  float* out0 = (float*)d_out;                   // [NLEN][BATCH][DIM] f32
  float* w = out0 + (size_t)NLEN * BATCH * DIM;  // weights [BATCH][NLEN][NLEN] f32

  u16* qp = (u16*)d_ws;                          // [B][N][D] bf16
  u16* qt = qp + (size_t)BATCH * NLEN * DIM;     // [B][D][N] bf16
  u16* mix0 = qt + (size_t)BATCH * NLEN * DIM;   // [B][N][D] bf16 partial
  u16* mix1 = mix0 + (size_t)BATCH * NLEN * DIM; // [B][N][D] bf16 partial
  u16* swf = mix1 + (size_t)BATCH * NLEN * DIM;  // packed tri tiles [B][136][128][128] bf16

  dim3 blk(256);
  k_qproj<<<dim3(DIM / 128, (BATCH * NLEN) / 128), blk, 0, stream>>>(query, W_in, qp, qt);
  k_scores<<<dim3(NLEN / 128, NLEN / 128, BATCH), blk, 0, stream>>>(qp, swf);
  k_softmax<<<dim3(NLEN, BATCH), blk, 0, stream>>>(swf, w);
  k_mix<<<dim3(384), blk, 0, stream>>>(swf, qt, mix0, mix1);
  k_out<<<dim3(DIM / 128, (BATCH * NLEN) / 128), blk, 0, stream>>>(mix0, mix1, qp, W_out, out0);
}

// Round 3
// 154.526 us; speedup vs baseline: 1.2986x; 1.0311x over previous
//
#include <hip/hip_runtime.h>
#include <hip/hip_bf16.h>

typedef unsigned short u16;
typedef unsigned int u32;

#define BATCH 4
#define NLEN 2048
#define DIM 512
#define LDSK 40   // 32 + 8 pad (u16), rows 80B apart

typedef __attribute__((ext_vector_type(8))) __bf16 bf16x8;
typedef __attribute__((ext_vector_type(4))) float f32x4;

__device__ __forceinline__ u16 f32_to_bf16(float f) {
  union { float f; u32 u; } v; v.f = f;
  u32 u = v.u;
  return (u16)((u + 0x7FFFu + ((u >> 16) & 1u)) >> 16);
}
__device__ __forceinline__ u32 pk2(float lo, float hi) {
  return (u32)f32_to_bf16(lo) | ((u32)f32_to_bf16(hi) << 16);
}
__device__ __forceinline__ void stage8_f32(u16* dst, const float* src) {
  float4 a = *(const float4*)src;
  float4 b = *(const float4*)(src + 4);
  uint4 o;
  o.x = pk2(a.x, a.y); o.y = pk2(a.z, a.w);
  o.z = pk2(b.x, b.y); o.w = pk2(b.z, b.w);
  *(uint4*)dst = o;
}
__device__ __forceinline__ void stage16_f32(u16* dst, const float* src) {
  stage8_f32(dst, src); stage8_f32(dst + 8, src + 8);
}
__device__ __forceinline__ void stage8_bf16(u16* dst, const u16* src) {
  *(uint4*)dst = *(const uint4*)src;
}
__device__ __forceinline__ void stage16_bf16(u16* dst, const u16* src) {
  *(uint4*)dst = *(const uint4*)src;
  *(uint4*)(dst + 8) = *(const uint4*)(src + 8);
}
// sum up to 3 bf16 partial streams (8 elems), f32 math, repack bf16
__device__ __forceinline__ void stage8_sum(u16* dst, const u16* s0, const u16* s1,
                                           const u16* s2, int cnt) {
  uint4 a = *(const uint4*)s0;
  u32 wa[4] = {a.x, a.y, a.z, a.w};
  float v[8];
#pragma unroll
  for (int i = 0; i < 4; ++i) {
    v[2 * i] = __uint_as_float(wa[i] << 16);
    v[2 * i + 1] = __uint_as_float(wa[i] & 0xffff0000u);
  }
  if (cnt > 1) {
    uint4 bq = *(const uint4*)s1;
    u32 wb[4] = {bq.x, bq.y, bq.z, bq.w};
#pragma unroll
    for (int i = 0; i < 4; ++i) {
      v[2 * i] += __uint_as_float(wb[i] << 16);
      v[2 * i + 1] += __uint_as_float(wb[i] & 0xffff0000u);
    }
  }
  if (cnt > 2) {
    uint4 cq = *(const uint4*)s2;
    u32 wc[4] = {cq.x, cq.y, cq.z, cq.w};
#pragma unroll
    for (int i = 0; i < 4; ++i) {
      v[2 * i] += __uint_as_float(wc[i] << 16);
      v[2 * i + 1] += __uint_as_float(wc[i] & 0xffff0000u);
    }
  }
  uint4 o;
  o.x = pk2(v[0], v[1]); o.y = pk2(v[2], v[3]);
  o.z = pk2(v[4], v[5]); o.w = pk2(v[6], v[7]);
  *(uint4*)dst = o;
}

template <int MR, int NR>
__device__ __forceinline__ void mma_tile(const u16* As, const u16* Bs, f32x4 acc[MR][NR],
                                         int wm, int wn, int lr, int lk) {
  bf16x8 af[MR], bfr[NR];
#pragma unroll
  for (int m = 0; m < MR; ++m)
    af[m] = *(const bf16x8*)(As + (wm + m * 16 + lr) * LDSK + lk);
#pragma unroll
  for (int n = 0; n < NR; ++n)
    bfr[n] = *(const bf16x8*)(Bs + (wn + n * 16 + lr) * LDSK + lk);
#pragma unroll
  for (int m = 0; m < MR; ++m)
#pragma unroll
    for (int n = 0; n < NR; ++n)
      acc[m][n] = __builtin_amdgcn_mfma_f32_16x16x32_bf16(af[m], bfr[n], acc[m][n], 0, 0, 0);
}

// ---------------- K1: q projection (64x128 tiles, 512 blocks) ----------------
__global__ __launch_bounds__(256) void k_qproj(const float* __restrict__ query,
                                               const float* __restrict__ W_in,
                                               u16* __restrict__ qp, u16* __restrict__ qt) {
  __shared__ u16 As[64 * LDSK];
  __shared__ u16 Bs[128 * LDSK];
  __shared__ u16 tbuf[128][72];  // [d_local][n_local+pad]
  const int t = threadIdx.x;
  const int lane = t & 63, wid = t >> 6;
  const int wm = (wid >> 1) * 32, wn = (wid & 1) * 64;
  const int lr = lane & 15, lk = (lane >> 4) * 8;
  const int trow4 = t >> 2, tseg = (t & 3) * 8;
  const int trow2 = t >> 1, thalf = (t & 1) * 16;
  const int rbase = blockIdx.y * 64;   // over b*n
  const int cbase = blockIdx.x * 128;  // over e
  const int rg = rbase + trow4;
  const int bb = rg >> 11, nn = rg & 2047;
  const float* aRow = query + (size_t)(nn * BATCH + bb) * DIM + tseg;
  const float* bRow = W_in + (size_t)(cbase + trow2) * DIM + thalf;
  f32x4 acc[2][4] = {};
  for (int k0 = 0; k0 < DIM; k0 += 32) {
    stage8_f32(As + trow4 * LDSK + tseg, aRow + k0);
    stage16_f32(Bs + trow2 * LDSK + thalf, bRow + k0);
    __syncthreads();
    mma_tile<2, 4>(As, Bs, acc, wm, wn, lr, lk);
    __syncthreads();
  }
#pragma unroll
  for (int m = 0; m < 2; ++m)
#pragma unroll
    for (int n = 0; n < 4; ++n)
#pragma unroll
      for (int j = 0; j < 4; ++j) {
        int rl = wm + m * 16 + (lane >> 4) * 4 + j;  // 0..63
        int cl = wn + n * 16 + lr;                   // 0..127
        u16 v = f32_to_bf16(acc[m][n][j]);
        qp[(size_t)(rbase + rl) * DIM + cbase + cl] = v;
        tbuf[cl][rl] = v;
      }
  __syncthreads();
  const int bb0 = rbase >> 11, nbase = rbase & 2047;
#pragma unroll
  for (int i = 0; i < 4; ++i) {
    int idx = t + i * 256;
    int dl = idx >> 3, c = idx & 7;
    uint4 v = *(const uint4*)&tbuf[dl][c * 8];
    *(uint4*)(qt + (size_t)(bb0 * DIM + cbase + dl) * NLEN + nbase + c * 8) = v;
  }
}

// ---------------- K2: scores (64x128 tiles) -> packed lower-tri bf16 128-tiles ----------------
__global__ __launch_bounds__(256) void k_scores(const u16* __restrict__ qp,
                                                u16* __restrict__ swf) {
  const int mt = blockIdx.x;   // 128-col tile (m), 0..15
  const int nt = blockIdx.y;   // 64-row tile (n), 0..31
  const int b = blockIdx.z;
  if (mt > (nt >> 1)) return;
  __shared__ u16 As[64 * LDSK];
  __shared__ u16 Bs[128 * LDSK];
  const int t = threadIdx.x;
  const int lane = t & 63, wid = t >> 6;
  const int wm = (wid >> 1) * 32, wn = (wid & 1) * 64;
  const int lr = lane & 15, lk = (lane >> 4) * 8;
  const int trow4 = t >> 2, tseg = (t & 3) * 8;
  const int trow2 = t >> 1, thalf = (t & 1) * 16;
  const u16* aRow = qp + (size_t)(b * NLEN + nt * 64 + trow4) * DIM + tseg;
  const u16* bRow = qp + (size_t)(b * NLEN + mt * 128 + trow2) * DIM + thalf;
  f32x4 acc[2][4] = {};
  for (int k0 = 0; k0 < DIM; k0 += 32) {
    stage8_bf16(As + trow4 * LDSK + tseg, aRow + k0);
    stage16_bf16(Bs + trow2 * LDSK + thalf, bRow + k0);
    __syncthreads();
    mma_tile<2, 4>(As, Bs, acc, wm, wn, lr, lk);
    __syncthreads();
  }
  const int NT = nt >> 1;
  u16* wtile = swf + ((size_t)(b * 136 + NT * (NT + 1) / 2 + mt) << 14);
  const int rowoff = (nt & 1) * 64;
#pragma unroll
  for (int m = 0; m < 2; ++m)
#pragma unroll
    for (int n = 0; n < 4; ++n)
#pragma unroll
      for (int j = 0; j < 4; ++j) {
        int rl = wm + m * 16 + (lane >> 4) * 4 + j;
        int cl = wn + n * 16 + lr;
        wtile[(rowoff + rl) * 128 + cl] = f32_to_bf16(acc[m][n][j]);
      }
}

// ---------------- K3: softmax: bf16 packed scores -> f32 weights + bf16 probs ----------------
__global__ __launch_bounds__(256) void k_softmax(u16* __restrict__ swf, float* __restrict__ w) {
  const int n = blockIdx.x, b = blockIdx.y;
  const int t = threadIdx.x;
  float* wrow = w + ((size_t)b * NLEN + n) * NLEN;
  const int nt = n >> 7;
  const size_t tb = ((size_t)(b * 136 + nt * (nt + 1) / 2) << 14) + ((size_t)(n & 127) << 7);
  __shared__ float srow[NLEN];
  __shared__ float red[4];
  if (n == 0) {
    for (int i = t; i < NLEN / 4; i += 256) ((float4*)wrow)[i] = float4{0, 0, 0, 0};
    if (t < 16) ((uint4*)(swf + tb))[t] = uint4{0, 0, 0, 0};
    return;
  }
  const int lane = t & 63, wid = t >> 6;
  const int nchunk = (nt + 1) * 16;
  float mx = -1e38f;
  for (int idx = t; idx < nchunk; idx += 256) {
    const int mt = idx >> 4, c = idx & 15;
    uint4 rv = *(const uint4*)(swf + tb + ((size_t)mt << 14) + c * 8);
    int m0 = mt * 128 + c * 8;
    u32 wds[4] = {rv.x, rv.y, rv.z, rv.w};
#pragma unroll
    for (int wi = 0; wi < 4; ++wi) {
      float v0 = __uint_as_float(wds[wi] << 16);
      float v1 = __uint_as_float(wds[wi] & 0xffff0000u);
      int m = m0 + wi * 2;
      srow[m] = v0; srow[m + 1] = v1;
      if (m < n) mx = fmaxf(mx, v0);
      if (m + 1 < n) mx = fmaxf(mx, v1);
    }
  }
#pragma unroll
  for (int off = 32; off; off >>= 1) mx = fmaxf(mx, __shfl_xor(mx, off));
  if (lane == 0) red[wid] = mx;
  __syncthreads();
  mx = fmaxf(fmaxf(red[0], red[1]), fmaxf(red[2], red[3]));
  float sum = 0.f;
  for (int m = t; m < n; m += 256) {
    float e = __expf(srow[m] - mx);
    srow[m] = e;
    sum += e;
  }
#pragma unroll
  for (int off = 32; off; off >>= 1) sum += __shfl_xor(sum, off);
  __syncthreads();
  if (lane == 0) red[wid] = sum;
  __syncthreads();
  float inv = 1.0f / (red[0] + red[1] + red[2] + red[3]);
  {
    int m0 = t * 8;
    float vals[8];
#pragma unroll
    for (int e = 0; e < 8; ++e) { int m = m0 + e; vals[e] = (m < n) ? srow[m] * inv : 0.f; }
    ((float4*)wrow)[t * 2] = float4{vals[0], vals[1], vals[2], vals[3]};
    ((float4*)wrow)[t * 2 + 1] = float4{vals[4], vals[5], vals[6], vals[7]};
  }
  for (int idx = t; idx < nchunk; idx += 256) {
    const int mt = idx >> 4, c = idx & 15;
    int m0 = mt * 128 + c * 8;
    u32 wo[4];
#pragma unroll
    for (int wi = 0; wi < 4; ++wi) {
      int m = m0 + wi * 2;
      float v0 = (m < n) ? srow[m] * inv : 0.f;
      float v1 = (m + 1 < n) ? srow[m + 1] * inv : 0.f;
      wo[wi] = (u32)f32_to_bf16(v0) | ((u32)f32_to_bf16(v1) << 16);
    }
    *(uint4*)(swf + tb + ((size_t)mt << 14) + c * 8) = uint4{wo[0], wo[1], wo[2], wo[3]};
  }
}

// ---------------- K4: mix partials, 3-way balanced split-K (528 blocks) ----------------
__global__ __launch_bounds__(256) void k_mix(const u16* __restrict__ swf,
                                             const u16* __restrict__ qt,
                                             u16* __restrict__ mixp) {
  const size_t PSZ = (size_t)BATCH * NLEN * DIM;
  const int bid = blockIdx.x;
  const int b = bid / 132;
  const int rem = bid % 132;
  const int dt = rem / 33;
  const int j = rem % 33;
  int nt, cp, P;
  if (j < 18) { nt = 15 - j / 3; cp = j % 3; P = 3; }
  else if (j < 28) { int jj = j - 18; nt = 9 - (jj >> 1); cp = jj & 1; P = 2; }
  else { nt = 32 - j; cp = 0; P = 1; }
  const int S = nt + 1;
  const int ks = cp * S / P, ke = (cp + 1) * S / P;
  __shared__ u16 As[128 * LDSK];
  __shared__ u16 Bs[128 * LDSK];
  const int t = threadIdx.x;
  const int lane = t & 63, wid = t >> 6;
  const int wm = (wid >> 1) * 64, wn = (wid & 1) * 64;
  const int lr = lane & 15, lk = (lane >> 4) * 8;
  const int trow2 = t >> 1, thalf = (t & 1) * 16;
  const size_t tribase = (size_t)(b * 136 + nt * (nt + 1) / 2) << 14;
  const u16* bRow = qt + (size_t)(b * DIM + dt * 128 + trow2) * NLEN + thalf;
  f32x4 acc[4][4] = {};
  for (int kstep = ks * 4; kstep < ke * 4; ++kstep) {
    const int k0 = kstep * 32;
    const int mt = k0 >> 7;
    const u16* aRow = swf + tribase + ((size_t)mt << 14) + trow2 * 128 + (k0 & 127) + thalf;
    stage16_bf16(As + trow2 * LDSK + thalf, aRow);
    stage16_bf16(Bs + trow2 * LDSK + thalf, bRow + k0);
    __syncthreads();
    mma_tile<4, 4>(As, Bs, acc, wm, wn, lr, lk);
    __syncthreads();
  }
  u16* dst = mixp + (size_t)cp * PSZ;
#pragma unroll
  for (int m = 0; m < 4; ++m)
#pragma unroll
    for (int n = 0; n < 4; ++n)
#pragma unroll
      for (int j2 = 0; j2 < 4; ++j2) {
        int row = nt * 128 + wm + m * 16 + (lane >> 4) * 4 + j2;
        int col = dt * 128 + wn + n * 16 + lr;
        dst[(size_t)(b * NLEN + row) * DIM + col] = f32_to_bf16(acc[m][n][j2]);
      }
}

// ---------------- K5: out = selu(concat(sum(mixp), q) . W_out^T)  (64x64 tiles, 1024 blocks) ----------------
__global__ __launch_bounds__(256) void k_out(const u16* __restrict__ mixp,
                                             const u16* __restrict__ qp,
                                             const float* __restrict__ W_out,
                                             float* __restrict__ out) {
  const size_t PSZ = (size_t)BATCH * NLEN * DIM;
  const int et = blockIdx.x;   // 8 col tiles of 64
  const int rt = blockIdx.y;   // 128 row tiles of 64
  __shared__ u16 As[64 * LDSK];
  __shared__ u16 Bs[64 * LDSK];
  const int t = threadIdx.x;
  const int lane = t & 63, wid = t >> 6;
  const int wm = (wid >> 1) * 32, wn = (wid & 1) * 32;
  const int lr = lane & 15, lk = (lane >> 4) * 8;
  const int trow4 = t >> 2, tseg = (t & 3) * 8;
  const int rbase = rt * 64;
  const int nt128 = (rbase & 2047) >> 7;
  const int cnt = (nt128 >= 10) ? 3 : ((nt128 >= 5) ? 2 : 1);
  const size_t arow = (size_t)(rbase + trow4) * DIM + tseg;
  const u16* m0 = mixp + arow;
  const u16* m1 = mixp + PSZ + arow;
  const u16* m2 = mixp + 2 * PSZ + arow;
  const u16* qr = qp + arow;
  const float* bRow = W_out + (size_t)(et * 64 + trow4) * (2 * DIM) + tseg;
  f32x4 acc[2][2] = {};
  for (int k0 = 0; k0 < 2 * DIM; k0 += 32) {
    if (k0 < DIM)
      stage8_sum(As + trow4 * LDSK + tseg, m0 + k0, m1 + k0, m2 + k0, cnt);
    else
      stage8_bf16(As + trow4 * LDSK + tseg, qr + (k0 - DIM));
    stage8_f32(Bs + trow4 * LDSK + tseg, bRow + k0);
    __syncthreads();
    mma_tile<2, 2>(As, Bs, acc, wm, wn, lr, lk);
    __syncthreads();
  }
  const float sc = 1.0507009873554805f;
  const float al = 1.6732632423543772f;
#pragma unroll
  for (int m = 0; m < 2; ++m)
#pragma unroll
    for (int n = 0; n < 2; ++n)
#pragma unroll
      for (int j = 0; j < 4; ++j) {
        int row = rbase + wm + m * 16 + (lane >> 4) * 4 + j;
        int col = et * 64 + wn + n * 16 + lr;
        int b2 = row >> 11, n2 = row & 2047;
        float v = acc[m][n][j];
        v = (v > 0.f) ? sc * v : sc * al * (__expf(v) - 1.f);
        out[(size_t)(n2 * BATCH + b2) * DIM + col] = v;
      }
}

extern "C" void kernel_launch(void* const* d_in, const int* in_sizes, int n_in,
                              void* d_out, int out_size, void* d_ws, size_t ws_size,
                              hipStream_t stream) {
  const float* query = (const float*)d_in[0];
  const float* W_in = (const float*)d_in[1];
  const float* W_out = (const float*)d_in[2];
  float* out0 = (float*)d_out;                   // [NLEN][BATCH][DIM] f32
  float* w = out0 + (size_t)NLEN * BATCH * DIM;  // weights [BATCH][NLEN][NLEN] f32

  const size_t PSZ = (size_t)BATCH * NLEN * DIM;
  u16* qp = (u16*)d_ws;            // [B][N][D] bf16
  u16* qt = qp + PSZ;              // [B][D][N] bf16
  u16* mixp = qt + PSZ;            // 3 partials [B][N][D] bf16
  u16* swf = mixp + 3 * PSZ;       // packed tri tiles [B][136][128][128] bf16

  dim3 blk(256);
  k_qproj<<<dim3(DIM / 128, (BATCH * NLEN) / 64), blk, 0, stream>>>(query, W_in, qp, qt);
  k_scores<<<dim3(16, 32, BATCH), blk, 0, stream>>>(qp, swf);
  k_softmax<<<dim3(NLEN, BATCH), blk, 0, stream>>>(swf, w);
  k_mix<<<dim3(528), blk, 0, stream>>>(swf, qt, mixp);
  k_out<<<dim3(8, 128), blk, 0, stream>>>(mixp, qp, W_out, out0);
}

// Round 4
// 139.529 us; speedup vs baseline: 1.4382x; 1.1075x over previous
//
#include <hip/hip_runtime.h>
#include <hip/hip_bf16.h>

typedef unsigned short u16;
typedef unsigned int u32;

#define BATCH 4
#define NLEN 2048
#define DIM 512
#define LDSK 40   // 32 + 8 pad (u16)
#define LDSB 72   // 64 + 8 pad (u16)

typedef __attribute__((ext_vector_type(8))) __bf16 bf16x8;
typedef __attribute__((ext_vector_type(4))) float f32x4;

__device__ __forceinline__ u16 f32_to_bf16(float f) {
  union { float f; u32 u; } v; v.f = f;
  u32 u = v.u;
  return (u16)((u + 0x7FFFu + ((u >> 16) & 1u)) >> 16);
}
__device__ __forceinline__ u32 pk2(float lo, float hi) {
  return (u32)f32_to_bf16(lo) | ((u32)f32_to_bf16(hi) << 16);
}
__device__ __forceinline__ void stage8_f32(u16* dst, const float* src) {
  float4 a = *(const float4*)src;
  float4 b = *(const float4*)(src + 4);
  uint4 o;
  o.x = pk2(a.x, a.y); o.y = pk2(a.z, a.w);
  o.z = pk2(b.x, b.y); o.w = pk2(b.z, b.w);
  *(uint4*)dst = o;
}
__device__ __forceinline__ void stage16_f32(u16* dst, const float* src) {
  stage8_f32(dst, src); stage8_f32(dst + 8, src + 8);
}
__device__ __forceinline__ void stage8_bf16(u16* dst, const u16* src) {
  *(uint4*)dst = *(const uint4*)src;
}
__device__ __forceinline__ void stage16_bf16(u16* dst, const u16* src) {
  *(uint4*)dst = *(const uint4*)src;
  *(uint4*)(dst + 8) = *(const uint4*)(src + 8);
}
// sum up to 3 bf16 partial streams (8 elems), f32 math, repack bf16
__device__ __forceinline__ void stage8_sum(u16* dst, const u16* s0, const u16* s1,
                                           const u16* s2, int cnt) {
  uint4 a = *(const uint4*)s0;
  u32 wa[4] = {a.x, a.y, a.z, a.w};
  float v[8];
#pragma unroll
  for (int i = 0; i < 4; ++i) {
    v[2 * i] = __uint_as_float(wa[i] << 16);
    v[2 * i + 1] = __uint_as_float(wa[i] & 0xffff0000u);
  }
  if (cnt > 1) {
    uint4 bq = *(const uint4*)s1;
    u32 wb[4] = {bq.x, bq.y, bq.z, bq.w};
#pragma unroll
    for (int i = 0; i < 4; ++i) {
      v[2 * i] += __uint_as_float(wb[i] << 16);
      v[2 * i + 1] += __uint_as_float(wb[i] & 0xffff0000u);
    }
  }
  if (cnt > 2) {
    uint4 cq = *(const uint4*)s2;
    u32 wc[4] = {cq.x, cq.y, cq.z, cq.w};
#pragma unroll
    for (int i = 0; i < 4; ++i) {
      v[2 * i] += __uint_as_float(wc[i] << 16);
      v[2 * i + 1] += __uint_as_float(wc[i] & 0xffff0000u);
    }
  }
  uint4 o;
  o.x = pk2(v[0], v[1]); o.y = pk2(v[2], v[3]);
  o.z = pk2(v[4], v[5]); o.w = pk2(v[6], v[7]);
  *(uint4*)dst = o;
}

template <int MR, int NR>
__device__ __forceinline__ void mma_tile(const u16* As, const u16* Bs, f32x4 acc[MR][NR],
                                         int wm, int wn, int lr, int lk) {
  bf16x8 af[MR], bfr[NR];
#pragma unroll
  for (int m = 0; m < MR; ++m)
    af[m] = *(const bf16x8*)(As + (wm + m * 16 + lr) * LDSK + lk);
#pragma unroll
  for (int n = 0; n < NR; ++n)
    bfr[n] = *(const bf16x8*)(Bs + (wn + n * 16 + lr) * LDSK + lk);
#pragma unroll
  for (int m = 0; m < MR; ++m)
#pragma unroll
    for (int n = 0; n < NR; ++n)
      acc[m][n] = __builtin_amdgcn_mfma_f32_16x16x32_bf16(af[m], bfr[n], acc[m][n], 0, 0, 0);
}

// ---------------- K1: q projection (64x128 tiles, 512 blocks) ----------------
__global__ __launch_bounds__(256) void k_qproj(const float* __restrict__ query,
                                               const float* __restrict__ W_in,
                                               u16* __restrict__ qp, u16* __restrict__ qt) {
  __shared__ u16 As[64 * LDSK];
  __shared__ u16 Bs[128 * LDSK];
  __shared__ u16 tbuf[128][72];
  const int t = threadIdx.x;
  const int lane = t & 63, wid = t >> 6;
  const int wm = (wid >> 1) * 32, wn = (wid & 1) * 64;
  const int lr = lane & 15, lk = (lane >> 4) * 8;
  const int trow4 = t >> 2, tseg = (t & 3) * 8;
  const int trow2 = t >> 1, thalf = (t & 1) * 16;
  const int rbase = blockIdx.y * 64;
  const int cbase = blockIdx.x * 128;
  const int rg = rbase + trow4;
  const int bb = rg >> 11, nn = rg & 2047;
  const float* aRow = query + (size_t)(nn * BATCH + bb) * DIM + tseg;
  const float* bRow = W_in + (size_t)(cbase + trow2) * DIM + thalf;
  f32x4 acc[2][4] = {};
  for (int k0 = 0; k0 < DIM; k0 += 32) {
    stage8_f32(As + trow4 * LDSK + tseg, aRow + k0);
    stage16_f32(Bs + trow2 * LDSK + thalf, bRow + k0);
    __syncthreads();
    mma_tile<2, 4>(As, Bs, acc, wm, wn, lr, lk);
    __syncthreads();
  }
#pragma unroll
  for (int m = 0; m < 2; ++m)
#pragma unroll
    for (int n = 0; n < 4; ++n)
#pragma unroll
      for (int j = 0; j < 4; ++j) {
        int rl = wm + m * 16 + (lane >> 4) * 4 + j;
        int cl = wn + n * 16 + lr;
        u16 v = f32_to_bf16(acc[m][n][j]);
        qp[(size_t)(rbase + rl) * DIM + cbase + cl] = v;
        tbuf[cl][rl] = v;
      }
  __syncthreads();
  const int bb0 = rbase >> 11, nbase = rbase & 2047;
#pragma unroll
  for (int i = 0; i < 4; ++i) {
    int idx = t + i * 256;
    int dl = idx >> 3, c = idx & 7;
    uint4 v = *(const uint4*)&tbuf[dl][c * 8];
    *(uint4*)(qt + (size_t)(bb0 * DIM + cbase + dl) * NLEN + nbase + c * 8) = v;
  }
}

// ---------------- K2: scores (64x128 tiles) -> packed lower-tri bf16 128-tiles ----------------
__global__ __launch_bounds__(256) void k_scores(const u16* __restrict__ qp,
                                                u16* __restrict__ swf) {
  const int mt = blockIdx.x;
  const int nt = blockIdx.y;
  const int b = blockIdx.z;
  if (mt > (nt >> 1)) return;
  __shared__ u16 As[64 * LDSK];
  __shared__ u16 Bs[128 * LDSK];
  const int t = threadIdx.x;
  const int lane = t & 63, wid = t >> 6;
  const int wm = (wid >> 1) * 32, wn = (wid & 1) * 64;
  const int lr = lane & 15, lk = (lane >> 4) * 8;
  const int trow4 = t >> 2, tseg = (t & 3) * 8;
  const int trow2 = t >> 1, thalf = (t & 1) * 16;
  const u16* aRow = qp + (size_t)(b * NLEN + nt * 64 + trow4) * DIM + tseg;
  const u16* bRow = qp + (size_t)(b * NLEN + mt * 128 + trow2) * DIM + thalf;
  f32x4 acc[2][4] = {};
  for (int k0 = 0; k0 < DIM; k0 += 32) {
    stage8_bf16(As + trow4 * LDSK + tseg, aRow + k0);
    stage16_bf16(Bs + trow2 * LDSK + thalf, bRow + k0);
    __syncthreads();
    mma_tile<2, 4>(As, Bs, acc, wm, wn, lr, lk);
    __syncthreads();
  }
  const int NT = nt >> 1;
  u16* wtile = swf + ((size_t)(b * 136 + NT * (NT + 1) / 2 + mt) << 14);
  const int rowoff = (nt & 1) * 64;
#pragma unroll
  for (int m = 0; m < 2; ++m)
#pragma unroll
    for (int n = 0; n < 4; ++n)
#pragma unroll
      for (int j = 0; j < 4; ++j) {
        int rl = wm + m * 16 + (lane >> 4) * 4 + j;
        int cl = wn + n * 16 + lr;
        wtile[(rowoff + rl) * 128 + cl] = f32_to_bf16(acc[m][n][j]);
      }
}

// ---------------- K3: softmax ----------------
__global__ __launch_bounds__(256) void k_softmax(u16* __restrict__ swf, float* __restrict__ w) {
  const int n = blockIdx.x, b = blockIdx.y;
  const int t = threadIdx.x;
  float* wrow = w + ((size_t)b * NLEN + n) * NLEN;
  const int nt = n >> 7;
  const size_t tb = ((size_t)(b * 136 + nt * (nt + 1) / 2) << 14) + ((size_t)(n & 127) << 7);
  __shared__ float srow[NLEN];
  __shared__ float red[4];
  if (n == 0) {
    for (int i = t; i < NLEN / 4; i += 256) ((float4*)wrow)[i] = float4{0, 0, 0, 0};
    if (t < 16) ((uint4*)(swf + tb))[t] = uint4{0, 0, 0, 0};
    return;
  }
  const int lane = t & 63, wid = t >> 6;
  const int nchunk = (nt + 1) * 16;
  float mx = -1e38f;
  for (int idx = t; idx < nchunk; idx += 256) {
    const int mt = idx >> 4, c = idx & 15;
    uint4 rv = *(const uint4*)(swf + tb + ((size_t)mt << 14) + c * 8);
    int m0 = mt * 128 + c * 8;
    u32 wds[4] = {rv.x, rv.y, rv.z, rv.w};
#pragma unroll
    for (int wi = 0; wi < 4; ++wi) {
      float v0 = __uint_as_float(wds[wi] << 16);
      float v1 = __uint_as_float(wds[wi] & 0xffff0000u);
      int m = m0 + wi * 2;
      srow[m] = v0; srow[m + 1] = v1;
      if (m < n) mx = fmaxf(mx, v0);
      if (m + 1 < n) mx = fmaxf(mx, v1);
    }
  }
#pragma unroll
  for (int off = 32; off; off >>= 1) mx = fmaxf(mx, __shfl_xor(mx, off));
  if (lane == 0) red[wid] = mx;
  __syncthreads();
  mx = fmaxf(fmaxf(red[0], red[1]), fmaxf(red[2], red[3]));
  float sum = 0.f;
  for (int m = t; m < n; m += 256) {
    float e = __expf(srow[m] - mx);
    srow[m] = e;
    sum += e;
  }
#pragma unroll
  for (int off = 32; off; off >>= 1) sum += __shfl_xor(sum, off);
  __syncthreads();
  if (lane == 0) red[wid] = sum;
  __syncthreads();
  float inv = 1.0f / (red[0] + red[1] + red[2] + red[3]);
  {
    int m0 = t * 8;
    float vals[8];
#pragma unroll
    for (int e = 0; e < 8; ++e) { int m = m0 + e; vals[e] = (m < n) ? srow[m] * inv : 0.f; }
    ((float4*)wrow)[t * 2] = float4{vals[0], vals[1], vals[2], vals[3]};
    ((float4*)wrow)[t * 2 + 1] = float4{vals[4], vals[5], vals[6], vals[7]};
  }
  for (int idx = t; idx < nchunk; idx += 256) {
    const int mt = idx >> 4, c = idx & 15;
    int m0 = mt * 128 + c * 8;
    u32 wo[4];
#pragma unroll
    for (int wi = 0; wi < 4; ++wi) {
      int m = m0 + wi * 2;
      float v0 = (m < n) ? srow[m] * inv : 0.f;
      float v1 = (m + 1 < n) ? srow[m + 1] * inv : 0.f;
      wo[wi] = (u32)f32_to_bf16(v0) | ((u32)f32_to_bf16(v1) << 16);
    }
    *(uint4*)(swf + tb + ((size_t)mt << 14) + c * 8) = uint4{wo[0], wo[1], wo[2], wo[3]};
  }
}

// ---------------- K4: mix partials, 3-way balanced split-K (528 blocks) ----------------
__global__ __launch_bounds__(256) void k_mix(const u16* __restrict__ swf,
                                             const u16* __restrict__ qt,
                                             u16* __restrict__ mixp) {
  const size_t PSZ = (size_t)BATCH * NLEN * DIM;
  const int bid = blockIdx.x;
  const int b = bid / 132;
  const int rem = bid % 132;
  const int dt = rem / 33;
  const int j = rem % 33;
  int nt, cp, P;
  if (j < 18) { nt = 15 - j / 3; cp = j % 3; P = 3; }
  else if (j < 28) { int jj = j - 18; nt = 9 - (jj >> 1); cp = jj & 1; P = 2; }
  else { nt = 32 - j; cp = 0; P = 1; }
  const int S = nt + 1;
  const int ks = cp * S / P, ke = (cp + 1) * S / P;
  __shared__ u16 As[128 * LDSK];
  __shared__ u16 Bs[128 * LDSK];
  const int t = threadIdx.x;
  const int lane = t & 63, wid = t >> 6;
  const int wm = (wid >> 1) * 64, wn = (wid & 1) * 64;
  const int lr = lane & 15, lk = (lane >> 4) * 8;
  const int trow2 = t >> 1, thalf = (t & 1) * 16;
  const size_t tribase = (size_t)(b * 136 + nt * (nt + 1) / 2) << 14;
  const u16* bRow = qt + (size_t)(b * DIM + dt * 128 + trow2) * NLEN + thalf;
  f32x4 acc[4][4] = {};
  for (int kstep = ks * 4; kstep < ke * 4; ++kstep) {
    const int k0 = kstep * 32;
    const int mt = k0 >> 7;
    const u16* aRow = swf + tribase + ((size_t)mt << 14) + trow2 * 128 + (k0 & 127) + thalf;
    stage16_bf16(As + trow2 * LDSK + thalf, aRow);
    stage16_bf16(Bs + trow2 * LDSK + thalf, bRow + k0);
    __syncthreads();
    mma_tile<4, 4>(As, Bs, acc, wm, wn, lr, lk);
    __syncthreads();
  }
  u16* dst = mixp + (size_t)cp * PSZ;
#pragma unroll
  for (int m = 0; m < 4; ++m)
#pragma unroll
    for (int n = 0; n < 4; ++n)
#pragma unroll
      for (int j2 = 0; j2 < 4; ++j2) {
        int row = nt * 128 + wm + m * 16 + (lane >> 4) * 4 + j2;
        int col = dt * 128 + wn + n * 16 + lr;
        dst[(size_t)(b * NLEN + row) * DIM + col] = f32_to_bf16(acc[m][n][j2]);
      }
}

// ---------------- K4b: fold partials -> amix ; convert W_out -> bf16 ----------------
__global__ __launch_bounds__(256) void k_fin(const u16* __restrict__ mixp,
                                             u16* __restrict__ amix,
                                             const float* __restrict__ W_out,
                                             u16* __restrict__ wob) {
  const size_t PSZ = (size_t)BATCH * NLEN * DIM;
  const int bid = blockIdx.x;
  const int t = threadIdx.x;
  if (bid < 512) {
#pragma unroll
    for (int i = 0; i < 4; ++i) {
      int g = i * 131072 + bid * 256 + t;  // uint4 index over [8192][64]
      int row = g >> 6, chunk = g & 63;
      int nt = (row & 2047) >> 7;
      int cnt = (nt >= 10) ? 3 : ((nt >= 5) ? 2 : 1);
      size_t off = (size_t)row * DIM + chunk * 8;
      stage8_sum(amix + off, mixp + off, mixp + PSZ + off, mixp + 2 * PSZ + off, cnt);
    }
  } else {
    int g = (bid - 512) * 256 + t;  // uint4 index over 512*1024 floats
    stage8_f32(wob + (size_t)g * 8, W_out + (size_t)g * 8);
  }
}

// ---------------- K5: out = selu([amix,q] . wob^T), 128x64 tiles, BK=64 ----------------
__global__ __launch_bounds__(256) void k_out(const u16* __restrict__ amix,
                                             const u16* __restrict__ qp,
                                             const u16* __restrict__ wob,
                                             float* __restrict__ out) {
  __shared__ u16 As[128 * LDSB];
  __shared__ u16 Bs[64 * LDSB];
  const int et = blockIdx.x;   // 8 col tiles of 64
  const int rt = blockIdx.y;   // 64 row tiles of 128
  const int t = threadIdx.x;
  const int lane = t & 63, wid = t >> 6;
  const int wm = (wid >> 1) * 64, wn = (wid & 1) * 32;
  const int lr = lane & 15, lk = (lane >> 4) * 8;
  const int rbase = rt * 128;
  const int ar = t >> 3, ac = (t & 7) * 8;   // A: 32 rows x 8 chunks per iter (x4)
  const int br = t >> 2, bc = (t & 3) * 16;  // B: 64 rows x 4 thr/row, 2 uint4 each
  const u16* aMix = amix + (size_t)rbase * DIM;
  const u16* aQ = qp + (size_t)rbase * DIM;
  const u16* bW = wob + (size_t)(et * 64 + br) * (2 * DIM) + bc;
  f32x4 acc[4][2] = {};
  for (int k0 = 0; k0 < 2 * DIM; k0 += 64) {
    const u16* asrc = (k0 < DIM) ? (aMix + k0) : (aQ + (k0 - DIM));
#pragma unroll
    for (int i = 0; i < 4; ++i)
      *(uint4*)(As + (ar + i * 32) * LDSB + ac) =
          *(const uint4*)(asrc + (size_t)(ar + i * 32) * DIM + ac);
    *(uint4*)(Bs + br * LDSB + bc) = *(const uint4*)(bW + k0);
    *(uint4*)(Bs + br * LDSB + bc + 8) = *(const uint4*)(bW + k0 + 8);
    __syncthreads();
#pragma unroll
    for (int kk = 0; kk < 64; kk += 32) {
      bf16x8 af[4], bfr[2];
#pragma unroll
      for (int m = 0; m < 4; ++m)
        af[m] = *(const bf16x8*)(As + (wm + m * 16 + lr) * LDSB + kk + lk);
#pragma unroll
      for (int n = 0; n < 2; ++n)
        bfr[n] = *(const bf16x8*)(Bs + (wn + n * 16 + lr) * LDSB + kk + lk);
#pragma unroll
      for (int m = 0; m < 4; ++m)
#pragma unroll
        for (int n = 0; n < 2; ++n)
          acc[m][n] = __builtin_amdgcn_mfma_f32_16x16x32_bf16(af[m], bfr[n], acc[m][n], 0, 0, 0);
    }
    __syncthreads();
  }
  const float sc = 1.0507009873554805f;
  const float al = 1.6732632423543772f;
#pragma unroll
  for (int m = 0; m < 4; ++m)
#pragma unroll
    for (int n = 0; n < 2; ++n)
#pragma unroll
      for (int j = 0; j < 4; ++j) {
        int row = rbase + wm + m * 16 + (lane >> 4) * 4 + j;
        int col = et * 64 + wn + n * 16 + lr;
        int b2 = row >> 11, n2 = row & 2047;
        float v = acc[m][n][j];
        v = (v > 0.f) ? sc * v : sc * al * (__expf(v) - 1.f);
        out[(size_t)(n2 * BATCH + b2) * DIM + col] = v;
      }
}

extern "C" void kernel_launch(void* const* d_in, const int* in_sizes, int n_in,
                              void* d_out, int out_size, void* d_ws, size_t ws_size,
                              hipStream_t stream) {
  const float* query = (const float*)d_in[0];
  const float* W_in = (const float*)d_in[1];
  const float* W_out = (const float*)d_in[2];
  float* out0 = (float*)d_out;                   // [NLEN][BATCH][DIM] f32
  float* w = out0 + (size_t)NLEN * BATCH * DIM;  // weights [BATCH][NLEN][NLEN] f32

  const size_t PSZ = (size_t)BATCH * NLEN * DIM;
  u16* qp = (u16*)d_ws;            // [B][N][D] bf16
  u16* qt = qp + PSZ;              // [B][D][N] bf16 ; aliased as amix after k_mix
  u16* mixp = qt + PSZ;            // 3 partials [B][N][D] bf16
  u16* swf = mixp + 3 * PSZ;       // packed tri tiles [B][136][128][128] bf16
  u16* wob = swf + (size_t)BATCH * 136 * 16384;  // W_out bf16 [512][1024]
  u16* amix = qt;                  // alias: qt dead after k_mix

  dim3 blk(256);
  k_qproj<<<dim3(DIM / 128, (BATCH * NLEN) / 64), blk, 0, stream>>>(query, W_in, qp, qt);
  k_scores<<<dim3(16, 32, BATCH), blk, 0, stream>>>(qp, swf);
  k_softmax<<<dim3(NLEN, BATCH), blk, 0, stream>>>(swf, w);
  k_mix<<<dim3(528), blk, 0, stream>>>(swf, qt, mixp);
  k_fin<<<dim3(768), blk, 0, stream>>>(mixp, amix, W_out, wob);
  k_out<<<dim3(8, 64), blk, 0, stream>>>(amix, qp, wob, out0);
}